// Round 19
// baseline (238.531 us; speedup 1.0000x reference)
//
#include <hip/hip_runtime.h>
#include <stdint.h>

typedef unsigned short u16;
typedef unsigned char u8;
typedef unsigned long long u64;
typedef __attribute__((ext_vector_type(8))) short bf16x8;
typedef __attribute__((ext_vector_type(4))) float f32x4;

#define KLOG2E 0.18033688011112043f   // SCALE(0.125) * log2(e)
#define QSCL 184.66496523378732f      // KLOG2E * 1024
#define SINV 0.0001220703125f         // 2^-13
#define EXP2F(x) __builtin_amdgcn_exp2f(x)
#define WAITV(n) asm volatile("s_waitcnt vmcnt(" #n ")" ::: "memory")

__device__ __forceinline__ u16 f2bf(float f) {
  union { float f; unsigned u; } v; v.f = f;
  unsigned r = v.u + 0x7fffu + ((v.u >> 16) & 1u);
  return (u16)(r >> 16);
}
__device__ __forceinline__ float bf2f(u16 u) {
  union { unsigned u; float f; } v; v.u = ((unsigned)u) << 16;
  return v.f;
}
__device__ __forceinline__ u8 f2fp8(float f) {
  return (u8)(__builtin_amdgcn_cvt_pk_fp8_f32(f, f, 0, false) & 0xFF);
}
__device__ __forceinline__ long pk64(uint2 v) {
  return (long)(((u64)v.y << 32) | (u64)v.x);
}

__device__ __forceinline__ void gload16(const void* g, void* l) {
  __builtin_amdgcn_global_load_lds(
      (const __attribute__((address_space(1))) unsigned int*)g,
      (__attribute__((address_space(3))) unsigned int*)l, 16, 0, 0);
}

// Fused f32->bf16 conversion for all 6 tensors (verified r15/r16). 1 launch.
__global__ void cvt_all(const float4* __restrict__ x, const float4* __restrict__ Wq,
                        const float4* __restrict__ Wk, const float4* __restrict__ Wv,
                        const float4* __restrict__ Wcb, const float4* __restrict__ Wproj,
                        uint2* __restrict__ xbf, uint2* __restrict__ Wqk,
                        uint2* __restrict__ Wvcb, uint2* __restrict__ Wpj) {
  int i = blockIdx.x * blockDim.x + threadIdx.x;
  int stride = gridDim.x * blockDim.x;
  for (; i < 2164992; i += stride) {
    const float4* s;
    uint2* d;
    if (i < 1572864) { s = x + i; d = xbf + i; }
    else {
      int j = i - 1572864;
      if (j < 147456) { s = Wq + j; d = Wqk + j; }
      else if (j < 294912) { s = Wk + (j - 147456); d = Wqk + 147456 + (j - 147456); }
      else if (j < 442368) { s = Wv + (j - 294912); d = Wvcb + (j - 294912); }
      else if (j < 589824) { s = Wproj + (j - 442368); d = Wpj + (j - 442368); }
      else { s = Wcb + (j - 589824); d = Wvcb + 147456 + (j - 589824); }
    }
    float4 v = *s;
    uint2 o;
    o.x = (unsigned)f2bf(v.x) | ((unsigned)f2bf(v.y) << 16);
    o.y = (unsigned)f2bf(v.z) | ((unsigned)f2bf(v.w) << 16);
    *d = o;
  }
}

// C = A @ B^T body, A [M,768] bf16, B [N,768] bf16, 128x128 tile, 4 waves.
// MODE 0: col<768 -> Qb bf16 [row][768]; col>=768 -> Kf8 fp8 x8 PERMUTED.
// MODE 1: vT+cb store; MODE 2: f32 C + bias[col].
template <int MODE>
__device__ __forceinline__ void gemm_body(
    u16* Ab, u16* Bb, int bx, int by,
    const u16* __restrict__ A, const u16* __restrict__ Bm,
    void* __restrict__ Cp, void* __restrict__ Cp2,
    const float* __restrict__ bias, int ldc) {
  const int tid = threadIdx.x;
  const int l = tid & 63, w = tid >> 6;
  const int g = l >> 4, l15 = l & 15;
  const int wr = w >> 1, wc = w & 1;
  const int rowbase = by * 128, colbase = bx * 128;

  f32x4 acc[4][4] = {};
  const char* Abase = (const char*)A + (size_t)rowbase * 1536;
  const char* Bbase = (const char*)Bm + (size_t)colbase * 1536;

  for (int kk = 0; kk < 768; kk += 32) {
    __syncthreads();
#pragma unroll
    for (int p = 0; p < 2; ++p) {
      int o = p * 4096 + w * 1024 + l * 16;
      int row = o >> 6, cb = o & 63;
      gload16(Abase + (size_t)row * 1536 + kk * 2 + cb, &Ab[(p * 4096 + w * 1024) / 2]);
      gload16(Bbase + (size_t)row * 1536 + kk * 2 + cb, &Bb[(p * 4096 + w * 1024) / 2]);
    }
    __syncthreads();
    bf16x8 af[4], bfr[4];
#pragma unroll
    for (int i = 0; i < 4; ++i) {
      af[i] = *(const bf16x8*)&Ab[(wr * 64 + i * 16 + l15) * 32 + g * 8];
      bfr[i] = *(const bf16x8*)&Bb[(wc * 64 + i * 16 + l15) * 32 + g * 8];
    }
#pragma unroll
    for (int mi = 0; mi < 4; ++mi)
#pragma unroll
      for (int ni = 0; ni < 4; ++ni)
        acc[mi][ni] = __builtin_amdgcn_mfma_f32_16x16x32_bf16(af[mi], bfr[ni], acc[mi][ni], 0, 0, 0);
  }

#pragma unroll
  for (int mi = 0; mi < 4; ++mi)
#pragma unroll
    for (int ni = 0; ni < 4; ++ni)
#pragma unroll
      for (int r = 0; r < 4; ++r) {
        int row = rowbase + wr * 64 + mi * 16 + g * 4 + r;
        int col = colbase + wc * 64 + ni * 16 + l15;
        float v = acc[mi][ni][r];
        if (MODE == 0) {
          if (col < 768) {
            ((u16*)Cp)[(size_t)row * 768 + col] = f2bf(v);
          } else {
            int d = col - 768;
            int chunk = d >> 7, w4 = (d >> 5) & 3, gg = (d >> 3) & 3, rr = d & 7;
            int dp = chunk * 128 + gg * 32 + w4 * 8 + rr;
            ((u8*)Cp2)[(size_t)row * 768 + dp] = f2fp8(v * 8.0f);
          }
        } else if (MODE == 2) {
          ((float*)Cp)[(size_t)row * ldc + col] = v + bias[col];
        } else {
          int b = col >> 10, nn = col & 1023;
          if (row < 768) {
            ((u16*)Cp)[(size_t)b * 786432 + (size_t)row * 1024 + nn] = f2bf(v + bias[row]);
          } else if (row < 780) {
            ((float*)Cp2)[(size_t)b * 12288 + (size_t)(row - 768) * 1024 + nn] = v * KLOG2E;
          }
        }
      }
}

// Fused MODE0 (768 blocks) + MODE1 (448 blocks) in one 1216-block launch.
__global__ __launch_bounds__(256, 2) void gemm_fused01(
    const u16* __restrict__ xbf, const u16* __restrict__ Wqk,
    u16* __restrict__ Qb, u8* __restrict__ Kf8,
    const u16* __restrict__ Wvcb, u16* __restrict__ vT,
    float* __restrict__ cbb, const float* __restrict__ bv) {
  __shared__ u16 Ab[128 * 32];
  __shared__ u16 Bb[128 * 32];
  int bid = blockIdx.x;
  if (bid < 768) {
    gemm_body<0>(Ab, Bb, bid % 12, bid / 12, xbf, Wqk, Qb, Kf8, nullptr, 0);
  } else {
    int j = bid - 768;
    gemm_body<1>(Ab, Bb, j % 64, j / 64, Wvcb, xbf, vT, cbb, bv, 0);
  }
}

__global__ __launch_bounds__(256, 2) void gemm_out(
    const u16* __restrict__ OH, const u16* __restrict__ Wpj,
    float* __restrict__ out, const float* __restrict__ bproj) {
  __shared__ u16 Ab[128 * 32];
  __shared__ u16 Bb[128 * 32];
  gemm_body<2>(Ab, Bb, blockIdx.x, blockIdx.y, OH, Wpj, out, nullptr, bproj, 768);
}

// Flash attention v19 = v14 structure (single-buffered V -> 48KB LDS -> 3
// blocks/CU -> grid 768 = exactly 1.0 dispatch waves, no tail), with NO
// launch_bounds: let the allocator pick its natural VGPR count (v8's body
// lands at 64 naturally; bounds hints drove v14/v15 into spill pathology).
__global__ void attn19(
    const u16* __restrict__ Qb,   // [B*N][768] bf16 (q_shared)
    const u8* __restrict__ Kf8,   // [B*N][768] fp8 e4m3 x8, permuted dims
    const u16* __restrict__ vT,   // [B][768][1024] bf16
    const float* __restrict__ cb, // [B][12][1024], pre-scaled by KLOG2E
    const float* __restrict__ Wmix,
    u16* __restrict__ OH)         // [B*N][768] bf16
{
  __shared__ u8 Kb[3][8192];    // 3-deep: 64 k-rows x 128B fp8 chunk, 16B-slot swz
  __shared__ u16 Vb[4096];      // single: [kwin2][64 d][4 slots x 16B]
  __shared__ u16 Pb[8][1024];   // per-wave P: [16 q][64 k] bf16, swz

  const int gid = blockIdx.x;
  const int b = gid & 7;
  const int within = gid >> 3;     // 0..95
  const int h = within % 12, qt = within / 12;  // qt 0..7
  const int tid = threadIdx.x;
  const int l = tid & 63, w = tid >> 6;
  const int g = l >> 4, l15 = l & 15;

  const u8* Ksrc = Kf8 + (size_t)b * 786432;
  const char* Vsrc = (const char*)vT + (size_t)(b * 12 + h) * 131072;
  const float* cbp = cb + (size_t)(b * 12 + h) * 1024;

  // ---- Q prologue: 16 q-rows x 768 d, x(Wmix*KLOG2E*1024), quantize fp8
  uint2 qreg[24];
  {
    const u16* qrow = Qb + ((size_t)b * 1024 + qt * 128 + w * 16 + l15) * 768;
    const float* wmh = Wmix + h * 768;
#pragma unroll
    for (int wd = 0; wd < 24; ++wd) {
      bf16x8 qv = *(const bf16x8*)(qrow + wd * 32 + g * 8);
      const float* wm = wmh + wd * 32 + g * 8;
      float4 w0 = *(const float4*)wm;
      float4 w1 = *(const float4*)(wm + 4);
      float q0 = bf2f((u16)qv[0]) * (w0.x * QSCL);
      float q1 = bf2f((u16)qv[1]) * (w0.y * QSCL);
      float q2 = bf2f((u16)qv[2]) * (w0.z * QSCL);
      float q3 = bf2f((u16)qv[3]) * (w0.w * QSCL);
      float q4 = bf2f((u16)qv[4]) * (w1.x * QSCL);
      float q5 = bf2f((u16)qv[5]) * (w1.y * QSCL);
      float q6 = bf2f((u16)qv[6]) * (w1.z * QSCL);
      float q7 = bf2f((u16)qv[7]) * (w1.w * QSCL);
      int a = __builtin_amdgcn_cvt_pk_fp8_f32(q0, q1, 0, false);
      a = __builtin_amdgcn_cvt_pk_fp8_f32(q2, q3, a, true);
      int b2 = __builtin_amdgcn_cvt_pk_fp8_f32(q4, q5, 0, false);
      b2 = __builtin_amdgcn_cvt_pk_fp8_f32(q6, q7, b2, true);
      qreg[wd].x = (unsigned)a;
      qreg[wd].y = (unsigned)b2;
    }
  }

  auto STK = [&](int kt, int ch, int buf) {
    int o = tid * 16;  // 512 thr x 16B = 8192B
    int row = o >> 7, t = (o >> 4) & 7;
    gload16(Ksrc + (size_t)(kt * 64 + row) * 768 + ch * 128 + ((t ^ (row & 7)) * 16),
            (char*)Kb[buf] + o);
  };
  auto STV = [&](int kt) {
    int o = tid * 16;
    int kwin = o >> 12, o2 = o & 4095, d = o2 >> 6, s = (o2 >> 4) & 3;
    gload16(Vsrc + (size_t)d * 2048 + (kt * 64 + kwin * 32 + ((s ^ (d & 3)) * 8)) * 2,
            (char*)Vb + o);
  };

  float m_run = -1e30f, lpart = 0.f;
  f32x4 oacc[4] = {};
  // prologue: stage chunks 0,1; full drain (__syncthreads emits vmcnt(0))
  STK(0, 0, 0);
  STK(0, 1, 1);
  __syncthreads();

  // FIFO wait table (simulated; V staged at ch0, drained by ch2's W1):
  //  ch0: +K(kt,2),+V(kt) -> W2   ch1: +K3 -> W2
  //  ch2: +K4 -> W1               ch3: +K5 -> W1
  //  ch4: +K(kt+1,0) -> W1 (tail W0)   ch5: +K(kt+1,1) -> W1 (tail W0)
  for (int kt = 0; kt < 16; ++kt) {
    f32x4 sa[4] = {};
#pragma unroll
    for (int ch = 0; ch < 6; ++ch) {
      if (ch == 0) STV(kt);
      if (ch <= 3) STK(kt, ch + 2, (ch + 2) % 3);
      else if (kt < 15) STK(kt + 1, ch - 4, (ch + 2) % 3);

      __builtin_amdgcn_s_setprio(1);
#pragma unroll
      for (int j = 0; j < 2; ++j) {
        long qf0 = pk64(qreg[ch * 4 + 2 * j]);
        long qf1 = pk64(qreg[ch * 4 + 2 * j + 1]);
        int slot = (2 * g + j) ^ (l15 & 7);
#pragma unroll
        for (int s = 0; s < 4; ++s) {
          uint4 kk = *(const uint4*)&Kb[ch % 3][(16 * s + l15) * 128 + slot * 16];
          long klo = (long)(((u64)kk.y << 32) | kk.x);
          long khi = (long)(((u64)kk.w << 32) | kk.z);
          sa[s] = __builtin_amdgcn_mfma_f32_16x16x32_fp8_fp8(klo, qf0, sa[s], 0, 0, 0);
          sa[s] = __builtin_amdgcn_mfma_f32_16x16x32_fp8_fp8(khi, qf1, sa[s], 0, 0, 0);
        }
      }
      __builtin_amdgcn_s_setprio(0);

      if (ch == 0 || ch == 1) { WAITV(2); }
      else if (ch == 2 || ch == 3) { WAITV(1); }
      else { if (kt < 15) { WAITV(1); } else { WAITV(0); } }
      __builtin_amdgcn_s_barrier();
    }

    // ---- softmax: lane holds rows k = 16s+4g+r for column q = l15
    float fv[16];
    float pmax = -1e30f;
#pragma unroll
    for (int s = 0; s < 4; ++s) {
      float4 cbv = *(const float4*)(cbp + kt * 64 + s * 16 + g * 4);
      fv[s * 4 + 0] = fmaf(sa[s][0], SINV, cbv.x);
      fv[s * 4 + 1] = fmaf(sa[s][1], SINV, cbv.y);
      fv[s * 4 + 2] = fmaf(sa[s][2], SINV, cbv.z);
      fv[s * 4 + 3] = fmaf(sa[s][3], SINV, cbv.w);
#pragma unroll
      for (int r = 0; r < 4; ++r) pmax = fmaxf(pmax, fv[s * 4 + r]);
    }
    pmax = fmaxf(pmax, __shfl_xor(pmax, 16));
    pmax = fmaxf(pmax, __shfl_xor(pmax, 32));
    if (__ballot(pmax > m_run)) {
      float mnew = fmaxf(m_run, pmax);
      float alpha = EXP2F(m_run - mnew);
      lpart *= alpha;
#pragma unroll
      for (int vf = 0; vf < 4; ++vf) oacc[vf] *= alpha;
      m_run = mnew;
    }
    float rs = 0.f;
#pragma unroll
    for (int r = 0; r < 16; ++r) {
      fv[r] = EXP2F(fv[r] - m_run);
      rs += fv[r];
    }
    rs += __shfl_xor(rs, 16);
    rs += __shfl_xor(rs, 32);
    lpart += rs;

    // ---- P pack -> per-wave LDS (b64 writes, 16B-slot swz)
#pragma unroll
    for (int s = 0; s < 4; ++s) {
      unsigned w01, w23;
      asm("v_cvt_pk_bf16_f32 %0, %1, %2" : "=v"(w01) : "v"(fv[s * 4]), "v"(fv[s * 4 + 1]));
      asm("v_cvt_pk_bf16_f32 %0, %1, %2" : "=v"(w23) : "v"(fv[s * 4 + 2]), "v"(fv[s * 4 + 3]));
      int ts = (2 * s + (g >> 1)) ^ (l15 & 7);
      uint2 uu; uu.x = w01; uu.y = w23;
      *(uint2*)((char*)Pb[w] + l15 * 128 + ts * 16 + (g & 1) * 8) = uu;
    }

    // ---- PV: A = V (16d x 32k) from single Vb, B = P from LDS
#pragma unroll
    for (int kwin = 0; kwin < 2; ++kwin) {
      int tr = (4 * kwin + g) ^ (l15 & 7);
      bf16x8 pf = *(const bf16x8*)((const char*)Pb[w] + l15 * 128 + tr * 16);
#pragma unroll
      for (int vf = 0; vf < 4; ++vf) {
        int d = vf * 16 + l15;
        bf16x8 vfrag = *(const bf16x8*)((const char*)Vb + kwin * 4096 + d * 64 +
                                        ((g ^ (d & 3)) * 16));
        oacc[vf] = __builtin_amdgcn_mfma_f32_16x16x32_bf16(vfrag, pf, oacc[vf], 0, 0, 0);
      }
    }
    // protect Vb: next kt's STV (at kt+1.ch0) must not overwrite before all
    // waves' PV reads complete.
    __builtin_amdgcn_s_barrier();
  }

  // ---- epilogue: lane (q=l15) holds d = vf*16+4g+r; divide by l, store u64
  float rdiv = 1.f / lpart;
  size_t nrow = ((size_t)b * 1024 + qt * 128 + w * 16 + l15) * 768;
#pragma unroll
  for (int vf = 0; vf < 4; ++vf) {
    u64 pk = (u64)f2bf(oacc[vf][0] * rdiv) |
             ((u64)f2bf(oacc[vf][1] * rdiv) << 16) |
             ((u64)f2bf(oacc[vf][2] * rdiv) << 32) |
             ((u64)f2bf(oacc[vf][3] * rdiv) << 48);
    *(u64*)&OH[nrow + h * 64 + vf * 16 + 4 * g] = pk;
  }
}

extern "C" void kernel_launch(void* const* d_in, const int* in_sizes, int n_in,
                              void* d_out, int out_size, void* d_ws, size_t ws_size,
                              hipStream_t stream) {
  (void)in_sizes; (void)n_in; (void)out_size; (void)ws_size;
  const float* x = (const float*)d_in[0];
  const float* Wq = (const float*)d_in[1];
  const float* Wk = (const float*)d_in[2];
  const float* Wv = (const float*)d_in[3];
  const float* bv = (const float*)d_in[4];
  const float* Wmix = (const float*)d_in[5];
  const float* Wcb = (const float*)d_in[6];
  const float* Wproj = (const float*)d_in[7];
  const float* bproj = (const float*)d_in[8];
  float* out = (float*)d_out;

  char* ws = (char*)d_ws;
  u16* xbf = (u16*)(ws);                 // 12582912 B
  u16* Wqk = (u16*)(ws + 12582912);      // 2359296 B
  u16* Wvcb = (u16*)(ws + 14942208);     // 1376256 B
  u16* Wpj = (u16*)(ws + 16318464);      // 1179648 B
  u16* Qb = (u16*)(ws + 17498112);       // 12582912 B
  u8* Kf8 = (u8*)(ws + 30081024);        // 6291456 B
  u16* vT = (u16*)(ws + 36372480);       // 12582912 B
  float* cbb = (float*)(ws + 48955392);  // 393216 B
  u16* OH = (u16*)(ws + 49348608);       // 12582912 B (end 61931520)

  cvt_all<<<2048, 256, 0, stream>>>((const float4*)x, (const float4*)Wq,
                                    (const float4*)Wk, (const float4*)Wv,
                                    (const float4*)Wcb, (const float4*)Wproj,
                                    (uint2*)xbf, (uint2*)Wqk, (uint2*)Wvcb, (uint2*)Wpj);

  gemm_fused01<<<1216, 256, 0, stream>>>(xbf, Wqk, Qb, Kf8, Wvcb, vT, cbb, bv);
  attn19<<<dim3(768), 512, 0, stream>>>(Qb, Kf8, vT, cbb, Wmix, OH);
  gemm_out<<<dim3(6, 64), 256, 0, stream>>>(OH, Wpj, out, bproj);
}

// Round 20
// 233.896 us; speedup vs baseline: 1.0198x; 1.0198x over previous
//
#include <hip/hip_runtime.h>
#include <stdint.h>

typedef unsigned short u16;
typedef unsigned char u8;
typedef unsigned long long u64;
typedef __attribute__((ext_vector_type(8))) short bf16x8;
typedef __attribute__((ext_vector_type(4))) float f32x4;

#define KLOG2E 0.18033688011112043f   // SCALE(0.125) * log2(e)
#define QSCL 184.66496523378732f      // KLOG2E * 1024
#define SINV 0.0001220703125f         // 2^-13
#define EXP2F(x) __builtin_amdgcn_exp2f(x)
#define WAITV(n) asm volatile("s_waitcnt vmcnt(" #n ")" ::: "memory")

__device__ __forceinline__ u16 f2bf(float f) {
  union { float f; unsigned u; } v; v.f = f;
  unsigned r = v.u + 0x7fffu + ((v.u >> 16) & 1u);
  return (u16)(r >> 16);
}
__device__ __forceinline__ float bf2f(u16 u) {
  union { unsigned u; float f; } v; v.u = ((unsigned)u) << 16;
  return v.f;
}
__device__ __forceinline__ u8 f2fp8(float f) {
  return (u8)(__builtin_amdgcn_cvt_pk_fp8_f32(f, f, 0, false) & 0xFF);
}
__device__ __forceinline__ long pk64(uint2 v) {
  return (long)(((u64)v.y << 32) | (u64)v.x);
}

__device__ __forceinline__ void gload16(const void* g, void* l) {
  __builtin_amdgcn_global_load_lds(
      (const __attribute__((address_space(1))) unsigned int*)g,
      (__attribute__((address_space(3))) unsigned int*)l, 16, 0, 0);
}

// Fused f32->bf16 conversion for all 6 tensors (verified r15/r16). 1 launch.
__global__ void cvt_all(const float4* __restrict__ x, const float4* __restrict__ Wq,
                        const float4* __restrict__ Wk, const float4* __restrict__ Wv,
                        const float4* __restrict__ Wcb, const float4* __restrict__ Wproj,
                        uint2* __restrict__ xbf, uint2* __restrict__ Wqk,
                        uint2* __restrict__ Wvcb, uint2* __restrict__ Wpj) {
  int i = blockIdx.x * blockDim.x + threadIdx.x;
  int stride = gridDim.x * blockDim.x;
  for (; i < 2164992; i += stride) {
    const float4* s;
    uint2* d;
    if (i < 1572864) { s = x + i; d = xbf + i; }
    else {
      int j = i - 1572864;
      if (j < 147456) { s = Wq + j; d = Wqk + j; }
      else if (j < 294912) { s = Wk + (j - 147456); d = Wqk + 147456 + (j - 147456); }
      else if (j < 442368) { s = Wv + (j - 294912); d = Wvcb + (j - 294912); }
      else if (j < 589824) { s = Wproj + (j - 442368); d = Wpj + (j - 442368); }
      else { s = Wcb + (j - 589824); d = Wvcb + 147456 + (j - 589824); }
    }
    float4 v = *s;
    uint2 o;
    o.x = (unsigned)f2bf(v.x) | ((unsigned)f2bf(v.y) << 16);
    o.y = (unsigned)f2bf(v.z) | ((unsigned)f2bf(v.w) << 16);
    *d = o;
  }
}

// C = A @ B^T body, A [M,768] bf16, B [N,768] bf16, 128x128 tile, 4 waves.
// MODE 0: col<768 -> Qb bf16 [row][768]; col>=768 -> Kf8 fp8 x8 PERMUTED.
// MODE 1: vT+cb store; MODE 2: f32 C + bias[col].
template <int MODE>
__device__ __forceinline__ void gemm_body(
    u16* Ab, u16* Bb, int bx, int by,
    const u16* __restrict__ A, const u16* __restrict__ Bm,
    void* __restrict__ Cp, void* __restrict__ Cp2,
    const float* __restrict__ bias, int ldc) {
  const int tid = threadIdx.x;
  const int l = tid & 63, w = tid >> 6;
  const int g = l >> 4, l15 = l & 15;
  const int wr = w >> 1, wc = w & 1;
  const int rowbase = by * 128, colbase = bx * 128;

  f32x4 acc[4][4] = {};
  const char* Abase = (const char*)A + (size_t)rowbase * 1536;
  const char* Bbase = (const char*)Bm + (size_t)colbase * 1536;

  for (int kk = 0; kk < 768; kk += 32) {
    __syncthreads();
#pragma unroll
    for (int p = 0; p < 2; ++p) {
      int o = p * 4096 + w * 1024 + l * 16;
      int row = o >> 6, cb = o & 63;
      gload16(Abase + (size_t)row * 1536 + kk * 2 + cb, &Ab[(p * 4096 + w * 1024) / 2]);
      gload16(Bbase + (size_t)row * 1536 + kk * 2 + cb, &Bb[(p * 4096 + w * 1024) / 2]);
    }
    __syncthreads();
    bf16x8 af[4], bfr[4];
#pragma unroll
    for (int i = 0; i < 4; ++i) {
      af[i] = *(const bf16x8*)&Ab[(wr * 64 + i * 16 + l15) * 32 + g * 8];
      bfr[i] = *(const bf16x8*)&Bb[(wc * 64 + i * 16 + l15) * 32 + g * 8];
    }
#pragma unroll
    for (int mi = 0; mi < 4; ++mi)
#pragma unroll
      for (int ni = 0; ni < 4; ++ni)
        acc[mi][ni] = __builtin_amdgcn_mfma_f32_16x16x32_bf16(af[mi], bfr[ni], acc[mi][ni], 0, 0, 0);
  }

#pragma unroll
  for (int mi = 0; mi < 4; ++mi)
#pragma unroll
    for (int ni = 0; ni < 4; ++ni)
#pragma unroll
      for (int r = 0; r < 4; ++r) {
        int row = rowbase + wr * 64 + mi * 16 + g * 4 + r;
        int col = colbase + wc * 64 + ni * 16 + l15;
        float v = acc[mi][ni][r];
        if (MODE == 0) {
          if (col < 768) {
            ((u16*)Cp)[(size_t)row * 768 + col] = f2bf(v);
          } else {
            int d = col - 768;
            int chunk = d >> 7, w4 = (d >> 5) & 3, gg = (d >> 3) & 3, rr = d & 7;
            int dp = chunk * 128 + gg * 32 + w4 * 8 + rr;
            ((u8*)Cp2)[(size_t)row * 768 + dp] = f2fp8(v * 8.0f);
          }
        } else if (MODE == 2) {
          ((float*)Cp)[(size_t)row * ldc + col] = v + bias[col];
        } else {
          int b = col >> 10, nn = col & 1023;
          if (row < 768) {
            ((u16*)Cp)[(size_t)b * 786432 + (size_t)row * 1024 + nn] = f2bf(v + bias[row]);
          } else if (row < 780) {
            ((float*)Cp2)[(size_t)b * 12288 + (size_t)(row - 768) * 1024 + nn] = v * KLOG2E;
          }
        }
      }
}

// Fused MODE0 (768 blocks) + MODE1 (448 blocks), one 1216-block launch,
// XCD-aware bijective block mapping: each XCD (gid&7) owns contiguous A/B
// panel groups so panel re-reads hit its private L2.
__global__ __launch_bounds__(256, 2) void gemm_fused01(
    const u16* __restrict__ xbf, const u16* __restrict__ Wqk,
    u16* __restrict__ Qb, u8* __restrict__ Kf8,
    const u16* __restrict__ Wvcb, u16* __restrict__ vT,
    float* __restrict__ cbb, const float* __restrict__ bv) {
  __shared__ u16 Ab[128 * 32];
  __shared__ u16 Bb[128 * 32];
  int bid = blockIdx.x;
  if (bid < 768) {
    // xcd = bid&7 -> by in [xcd*8, xcd*8+8): A-panels L2-local per XCD
    int xcd = bid & 7, idx = bid >> 3;           // idx 0..95
    int by = xcd * 8 + idx / 12, bx = idx % 12;  // bijective
    gemm_body<0>(Ab, Bb, bx, by, xbf, Wqk, Qb, Kf8, nullptr, 0);
  } else {
    int j = bid - 768;                           // 0..447
    int xcd = j & 7, idx = j >> 3;               // idx 0..55
    int bx = xcd * 8 + idx / 7, by = idx % 7;    // bijective; B-panels L2-local
    gemm_body<1>(Ab, Bb, bx, by, Wvcb, xbf, vT, cbb, bv, 0);
  }
}

__global__ __launch_bounds__(256, 2) void gemm_out(
    const u16* __restrict__ OH, const u16* __restrict__ Wpj,
    float* __restrict__ out, const float* __restrict__ bproj) {
  __shared__ u16 Ab[128 * 32];
  __shared__ u16 Bb[128 * 32];
  gemm_body<2>(Ab, Bb, blockIdx.x, blockIdx.y, OH, Wpj, out, nullptr, bproj, 768);
}

// Flash attention v8 dataflow VERBATIM (171.5 us, VGPR 64, no spill), (512,4).
__global__ __launch_bounds__(512, 4) void attn8(
    const u16* __restrict__ Qb,   // [B*N][768] bf16 (q_shared)
    const u8* __restrict__ Kf8,   // [B*N][768] fp8 e4m3 x8, permuted dims
    const u16* __restrict__ vT,   // [B][768][1024] bf16
    const float* __restrict__ cb, // [B][12][1024], pre-scaled by KLOG2E
    const float* __restrict__ Wmix,
    u16* __restrict__ OH)         // [B*N][768] bf16
{
  __shared__ u8 Kb[3][8192];    // 3-deep: 64 k-rows x 128B fp8 chunk, 16B-slot swz
  __shared__ u16 Vb[2][4096];   // dbuf: [kwin2][64 d][4 slots x 16B]
  __shared__ u16 Pb[8][1024];   // per-wave P: [16 q][64 k] bf16, swz

  const int gid = blockIdx.x;
  const int b = gid & 7;
  const int within = gid >> 3;     // 0..95
  const int h = within % 12, qt = within / 12;  // qt 0..7
  const int tid = threadIdx.x;
  const int l = tid & 63, w = tid >> 6;
  const int g = l >> 4, l15 = l & 15;

  const u8* Ksrc = Kf8 + (size_t)b * 786432;
  const char* Vsrc = (const char*)vT + (size_t)(b * 12 + h) * 131072;
  const float* cbp = cb + (size_t)(b * 12 + h) * 1024;

  // ---- Q prologue: 16 q-rows x 768 d, x(Wmix*KLOG2E*1024), quantize fp8
  uint2 qreg[24];
  {
    const u16* qrow = Qb + ((size_t)b * 1024 + qt * 128 + w * 16 + l15) * 768;
    const float* wmh = Wmix + h * 768;
#pragma unroll
    for (int wd = 0; wd < 24; ++wd) {
      bf16x8 qv = *(const bf16x8*)(qrow + wd * 32 + g * 8);
      const float* wm = wmh + wd * 32 + g * 8;
      float4 w0 = *(const float4*)wm;
      float4 w1 = *(const float4*)(wm + 4);
      float q0 = bf2f((u16)qv[0]) * (w0.x * QSCL);
      float q1 = bf2f((u16)qv[1]) * (w0.y * QSCL);
      float q2 = bf2f((u16)qv[2]) * (w0.z * QSCL);
      float q3 = bf2f((u16)qv[3]) * (w0.w * QSCL);
      float q4 = bf2f((u16)qv[4]) * (w1.x * QSCL);
      float q5 = bf2f((u16)qv[5]) * (w1.y * QSCL);
      float q6 = bf2f((u16)qv[6]) * (w1.z * QSCL);
      float q7 = bf2f((u16)qv[7]) * (w1.w * QSCL);
      int a = __builtin_amdgcn_cvt_pk_fp8_f32(q0, q1, 0, false);
      a = __builtin_amdgcn_cvt_pk_fp8_f32(q2, q3, a, true);
      int b2 = __builtin_amdgcn_cvt_pk_fp8_f32(q4, q5, 0, false);
      b2 = __builtin_amdgcn_cvt_pk_fp8_f32(q6, q7, b2, true);
      qreg[wd].x = (unsigned)a;
      qreg[wd].y = (unsigned)b2;
    }
  }

  auto STK = [&](int kt, int ch, int buf) {
    int o = tid * 16;  // 512 thr x 16B = 8192B
    int row = o >> 7, t = (o >> 4) & 7;
    gload16(Ksrc + (size_t)(kt * 64 + row) * 768 + ch * 128 + ((t ^ (row & 7)) * 16),
            (char*)Kb[buf] + o);
  };
  auto STV = [&](int kt, int buf) {
    int o = tid * 16;
    int kwin = o >> 12, o2 = o & 4095, d = o2 >> 6, s = (o2 >> 4) & 3;
    gload16(Vsrc + (size_t)d * 2048 + (kt * 64 + kwin * 32 + ((s ^ (d & 3)) * 8)) * 2,
            (char*)Vb[buf] + o);
  };

  float m_run = -1e30f, lpart = 0.f;
  f32x4 oacc[4] = {};
  // prologue: stage phases 0,1 and V(kt0); single full drain
  STK(0, 0, 0);
  STK(0, 1, 1);
  STV(0, 0);
  __syncthreads();

  for (int kt = 0; kt < 16; ++kt) {
    f32x4 sa[4] = {};
#pragma unroll
    for (int ch = 0; ch < 6; ++ch) {
      // ---- stage (phase+2): V first at ch1 so it drains with W=2
      if (ch == 1 && kt < 15) STV(kt + 1, (kt + 1) & 1);
      if (ch <= 3) STK(kt, ch + 2, (ch + 2) % 3);
      else if (kt < 15) STK(kt + 1, ch - 4, (ch + 2) % 3);
      // ---- compute chunk ch from Kb[ch%3]
      __builtin_amdgcn_s_setprio(1);
#pragma unroll
      for (int j = 0; j < 2; ++j) {
        long qf0 = pk64(qreg[ch * 4 + 2 * j]);
        long qf1 = pk64(qreg[ch * 4 + 2 * j + 1]);
        int slot = (2 * g + j) ^ (l15 & 7);
#pragma unroll
        for (int s = 0; s < 4; ++s) {
          uint4 kk = *(const uint4*)&Kb[ch % 3][(16 * s + l15) * 128 + slot * 16];
          long klo = (long)(((u64)kk.y << 32) | kk.x);
          long khi = (long)(((u64)kk.w << 32) | kk.z);
          sa[s] = __builtin_amdgcn_mfma_f32_16x16x32_fp8_fp8(klo, qf0, sa[s], 0, 0, 0);
          sa[s] = __builtin_amdgcn_mfma_f32_16x16x32_fp8_fp8(khi, qf1, sa[s], 0, 0, 0);
        }
      }
      __builtin_amdgcn_s_setprio(0);
      // ---- counted wait + barrier (no drain in steady state)
      if (ch == 1) {
        if (kt < 15) { WAITV(2); } else { WAITV(1); }
      } else if (ch >= 4) {
        if (kt < 15) { WAITV(1); } else { WAITV(0); }
      } else {
        WAITV(1);
      }
      __builtin_amdgcn_s_barrier();
    }

    // ---- softmax: lane holds rows k = 16s+4g+r for column q = l15
    float fv[16];
    float pmax = -1e30f;
#pragma unroll
    for (int s = 0; s < 4; ++s) {
      float4 cbv = *(const float4*)(cbp + kt * 64 + s * 16 + g * 4);
      fv[s * 4 + 0] = fmaf(sa[s][0], SINV, cbv.x);
      fv[s * 4 + 1] = fmaf(sa[s][1], SINV, cbv.y);
      fv[s * 4 + 2] = fmaf(sa[s][2], SINV, cbv.z);
      fv[s * 4 + 3] = fmaf(sa[s][3], SINV, cbv.w);
#pragma unroll
      for (int r = 0; r < 4; ++r) pmax = fmaxf(pmax, fv[s * 4 + r]);
    }
    pmax = fmaxf(pmax, __shfl_xor(pmax, 16));
    pmax = fmaxf(pmax, __shfl_xor(pmax, 32));
    if (__ballot(pmax > m_run)) {
      float mnew = fmaxf(m_run, pmax);
      float alpha = EXP2F(m_run - mnew);
      lpart *= alpha;
#pragma unroll
      for (int vf = 0; vf < 4; ++vf) oacc[vf] *= alpha;
      m_run = mnew;
    }
    float rs = 0.f;
#pragma unroll
    for (int r = 0; r < 16; ++r) {
      fv[r] = EXP2F(fv[r] - m_run);
      rs += fv[r];
    }
    rs += __shfl_xor(rs, 16);
    rs += __shfl_xor(rs, 32);
    lpart += rs;

    // ---- P pack -> per-wave LDS (b64 writes, 16B-slot swz)
#pragma unroll
    for (int s = 0; s < 4; ++s) {
      unsigned w01, w23;
      asm("v_cvt_pk_bf16_f32 %0, %1, %2" : "=v"(w01) : "v"(fv[s * 4]), "v"(fv[s * 4 + 1]));
      asm("v_cvt_pk_bf16_f32 %0, %1, %2" : "=v"(w23) : "v"(fv[s * 4 + 2]), "v"(fv[s * 4 + 3]));
      int ts = (2 * s + (g >> 1)) ^ (l15 & 7);
      uint2 uu; uu.x = w01; uu.y = w23;
      *(uint2*)((char*)Pb[w] + l15 * 128 + ts * 16 + (g & 1) * 8) = uu;
    }

    // ---- PV: A = V (16d x 32k) from LDS, B = P from LDS (V of kt: Vb[kt&1])
#pragma unroll
    for (int kwin = 0; kwin < 2; ++kwin) {
      int tr = (4 * kwin + g) ^ (l15 & 7);
      bf16x8 pf = *(const bf16x8*)((const char*)Pb[w] + l15 * 128 + tr * 16);
#pragma unroll
      for (int vf = 0; vf < 4; ++vf) {
        int d = vf * 16 + l15;
        bf16x8 vfrag = *(const bf16x8*)((const char*)Vb[kt & 1] + kwin * 4096 + d * 64 +
                                        ((g ^ (d & 3)) * 16));
        oacc[vf] = __builtin_amdgcn_mfma_f32_16x16x32_bf16(vfrag, pf, oacc[vf], 0, 0, 0);
      }
    }
  }

  // ---- epilogue: lane (q=l15) holds d = vf*16+4g+r; divide by l, store u64
  float rdiv = 1.f / lpart;
  size_t nrow = ((size_t)b * 1024 + qt * 128 + w * 16 + l15) * 768;
#pragma unroll
  for (int vf = 0; vf < 4; ++vf) {
    u64 pk = (u64)f2bf(oacc[vf][0] * rdiv) |
             ((u64)f2bf(oacc[vf][1] * rdiv) << 16) |
             ((u64)f2bf(oacc[vf][2] * rdiv) << 32) |
             ((u64)f2bf(oacc[vf][3] * rdiv) << 48);
    *(u64*)&OH[nrow + h * 64 + vf * 16 + 4 * g] = pk;
  }
}

extern "C" void kernel_launch(void* const* d_in, const int* in_sizes, int n_in,
                              void* d_out, int out_size, void* d_ws, size_t ws_size,
                              hipStream_t stream) {
  (void)in_sizes; (void)n_in; (void)out_size; (void)ws_size;
  const float* x = (const float*)d_in[0];
  const float* Wq = (const float*)d_in[1];
  const float* Wk = (const float*)d_in[2];
  const float* Wv = (const float*)d_in[3];
  const float* bv = (const float*)d_in[4];
  const float* Wmix = (const float*)d_in[5];
  const float* Wcb = (const float*)d_in[6];
  const float* Wproj = (const float*)d_in[7];
  const float* bproj = (const float*)d_in[8];
  float* out = (float*)d_out;

  char* ws = (char*)d_ws;
  u16* xbf = (u16*)(ws);                 // 12582912 B
  u16* Wqk = (u16*)(ws + 12582912);      // 2359296 B
  u16* Wvcb = (u16*)(ws + 14942208);     // 1376256 B
  u16* Wpj = (u16*)(ws + 16318464);      // 1179648 B
  u16* Qb = (u16*)(ws + 17498112);       // 12582912 B
  u8* Kf8 = (u8*)(ws + 30081024);        // 6291456 B
  u16* vT = (u16*)(ws + 36372480);       // 12582912 B
  float* cbb = (float*)(ws + 48955392);  // 393216 B
  u16* OH = (u16*)(ws + 49348608);       // 12582912 B (end 61931520)

  cvt_all<<<2048, 256, 0, stream>>>((const float4*)x, (const float4*)Wq,
                                    (const float4*)Wk, (const float4*)Wv,
                                    (const float4*)Wcb, (const float4*)Wproj,
                                    (uint2*)xbf, (uint2*)Wqk, (uint2*)Wvcb, (uint2*)Wpj);

  gemm_fused01<<<1216, 256, 0, stream>>>(xbf, Wqk, Qb, Kf8, Wvcb, vT, cbb, bv);
  attn8<<<dim3(768), 512, 0, stream>>>(Qb, Kf8, vT, cbb, Wmix, OH);
  gemm_out<<<dim3(6, 64), 256, 0, stream>>>(OH, Wpj, out, bproj);
}